// Round 4
// baseline (57.658 us; speedup 1.0000x reference)
//
#include <hip/hip_runtime.h>

typedef unsigned short u16;
typedef __attribute__((ext_vector_type(4))) float f32x4;
typedef __attribute__((ext_vector_type(8))) short short8;

#define D0 784
#define D1 128
#define D2 64
#define D3 10
#define KS0 25
#define KS1 4
#define KS2 2

// workspace byte offsets
#define WS_W0P 0        // 25*128*32 u16 = 204800 B
#define WS_W1P 204800   // 4*64*32 u16   = 16384 B
#define WS_W2P 221184   // 2*16*32 u16   = 2048 B
#define WS_B0  223232   // 128 f32
#define WS_B1  223744   // 64 f32
#define WS_B2  224000   // 16 f32

__device__ __forceinline__ u16 f2bf(float f) {
  union { float f; unsigned u; } v; v.f = f;
  unsigned u = v.u;
  return (u16)((u + 0x7fffu + ((u >> 16) & 1u)) >> 16);  // RNE f32->bf16
}

// plain pack: [ks][col][32] bf16 k-step tiles (B-frags read straight from L2)
__global__ void prep_kernel(const float* __restrict__ W0, const float* __restrict__ W1,
                            const float* __restrict__ W2, u16* __restrict__ w0p,
                            u16* __restrict__ w1p, u16* __restrict__ w2p,
                            float* __restrict__ b0, float* __restrict__ b1,
                            float* __restrict__ b2) {
  int idx = blockIdx.x * 256 + threadIdx.x;
  if (idx < 25 * 128 * 32) {  // W0: [785][128] -> [25][128][32] (k zero-padded)
    int ks = idx / 4096, rem = idx % 4096, c = rem >> 5, kk = rem & 31;
    int k = ks * 32 + kk;
    float v = (k < D0) ? W0[k * D1 + c] : 0.f;
    w0p[ks * 4096 + c * 32 + kk] = f2bf(v);
    return;
  }
  idx -= 25 * 128 * 32;
  if (idx < 4 * 64 * 32) {  // W1: [129][64] -> [4][64][32]
    int ks = idx / 2048, rem = idx % 2048, c = rem >> 5, kk = rem & 31;
    int k = ks * 32 + kk;
    w1p[ks * 2048 + c * 32 + kk] = f2bf(W1[k * D2 + c]);
    return;
  }
  idx -= 4 * 64 * 32;
  if (idx < 2 * 16 * 32) {  // W2: [65][10] -> [2][16][32] (cols padded to 16)
    int ks = idx / 512, rem = idx % 512, c = rem >> 5, kk = rem & 31;
    int k = ks * 32 + kk;
    float v = (c < D3) ? W2[k * D3 + c] : 0.f;
    w2p[ks * 512 + c * 32 + kk] = f2bf(v);
    return;
  }
  idx -= 2 * 16 * 32;
  if (idx < 128) { b0[idx] = W0[D0 * D1 + idx]; return; }
  idx -= 128;
  if (idx < 64) { b1[idx] = W1[D1 * D2 + idx]; return; }
  idx -= 64;
  if (idx < 16) { b2[idx] = (idx < D3) ? W2[D2 * D3 + idx] : 0.f; }
}

__device__ __forceinline__ void cvtpk(unsigned& d, float lo, float hi) {
  asm("v_cvt_pk_bf16_f32 %0, %1, %2" : "=v"(d) : "v"(lo), "v"(hi));
}

// Barrier-free fused MLP: every wave independent through all 3 layers.
// 32 rows/wave (2 A-frags), B-frags loaded directly from L2-resident packed
// weights, LDS only as per-wave h0/h1 transpose scratch.
__global__ __launch_bounds__(256, 2) void mlp_fused(
    const float* __restrict__ X, const u16* __restrict__ w0p,
    const u16* __restrict__ w1p, const u16* __restrict__ w2p,
    const float* __restrict__ b0, const float* __restrict__ b1,
    const float* __restrict__ b2, float* __restrict__ out) {
  __shared__ __attribute__((aligned(16))) u16 smH[4][4096];  // 8 KB per wave

  const int t = threadIdx.x;
  const int lane = t & 63;
  const int wv = t >> 6;
  const int q = lane >> 4;    // k-chunk (A/B) / row-group (C)
  const int lr = lane & 15;   // A row / B,C col within fragment

  const int rowbase = blockIdx.x * 128 + wv * 32;
  const float* xr0 = X + (size_t)(rowbase + lr) * D0;        // rows 0..15 of strip
  const float* xr1 = xr0 + (size_t)16 * D0;                  // rows 16..31
  const u16* bp0 = w0p + lr * 32 + q * 8;                    // + ks*4096 + f*512

  f32x4 acc[2][8];
#pragma unroll
  for (int m = 0; m < 2; ++m)
#pragma unroll
    for (int f = 0; f < 8; ++f) acc[m][f] = (f32x4){0.f, 0.f, 0.f, 0.f};

  // main k-steps 0..23: all 32 k's in range (23*32+31 = 767 < 784)
#pragma unroll
  for (int ks = 0; ks < KS0 - 1; ++ks) {
    const f32x4* xp0 = (const f32x4*)(xr0 + ks * 32 + q * 8);
    const f32x4* xp1 = (const f32x4*)(xr1 + ks * 32 + q * 8);
    f32x4 x0a = xp0[0], x0b = xp0[1];
    f32x4 x1a = xp1[0], x1b = xp1[1];
    short8 b[8];
#pragma unroll
    for (int f = 0; f < 8; ++f)
      b[f] = *(const short8*)(bp0 + ks * 4096 + f * 512);
    union { short8 s; unsigned u[4]; } a0, a1;
    cvtpk(a0.u[0], x0a[0], x0a[1]); cvtpk(a0.u[1], x0a[2], x0a[3]);
    cvtpk(a0.u[2], x0b[0], x0b[1]); cvtpk(a0.u[3], x0b[2], x0b[3]);
    cvtpk(a1.u[0], x1a[0], x1a[1]); cvtpk(a1.u[1], x1a[2], x1a[3]);
    cvtpk(a1.u[2], x1b[0], x1b[1]); cvtpk(a1.u[3], x1b[2], x1b[3]);
#pragma unroll
    for (int f = 0; f < 8; ++f) {
      acc[0][f] = __builtin_amdgcn_mfma_f32_16x16x32_bf16(a0.s, b[f], acc[0][f], 0, 0, 0);
      acc[1][f] = __builtin_amdgcn_mfma_f32_16x16x32_bf16(a1.s, b[f], acc[1][f], 0, 0, 0);
    }
  }
  // tail k-step 24: k = 768..799, only 768..783 valid. Lanes q>=2 would read
  // past the row (and past X for the final row) -> give them zero A-frags;
  // exact because W0p rows k>=784 are zero-padded.
  {
    const int ks = KS0 - 1;
    f32x4 x0a = (f32x4){0.f, 0.f, 0.f, 0.f}, x0b = x0a, x1a = x0a, x1b = x0a;
    if (q < 2) {
      const f32x4* xp0 = (const f32x4*)(xr0 + ks * 32 + q * 8);
      const f32x4* xp1 = (const f32x4*)(xr1 + ks * 32 + q * 8);
      x0a = xp0[0]; x0b = xp0[1];
      x1a = xp1[0]; x1b = xp1[1];
    }
    short8 b[8];
#pragma unroll
    for (int f = 0; f < 8; ++f)
      b[f] = *(const short8*)(bp0 + ks * 4096 + f * 512);
    union { short8 s; unsigned u[4]; } a0, a1;
    cvtpk(a0.u[0], x0a[0], x0a[1]); cvtpk(a0.u[1], x0a[2], x0a[3]);
    cvtpk(a0.u[2], x0b[0], x0b[1]); cvtpk(a0.u[3], x0b[2], x0b[3]);
    cvtpk(a1.u[0], x1a[0], x1a[1]); cvtpk(a1.u[1], x1a[2], x1a[3]);
    cvtpk(a1.u[2], x1b[0], x1b[1]); cvtpk(a1.u[3], x1b[2], x1b[3]);
#pragma unroll
    for (int f = 0; f < 8; ++f) {
      acc[0][f] = __builtin_amdgcn_mfma_f32_16x16x32_bf16(a0.s, b[f], acc[0][f], 0, 0, 0);
      acc[1][f] = __builtin_amdgcn_mfma_f32_16x16x32_bf16(a1.s, b[f], acc[1][f], 0, 0, 0);
    }
  }

  // ---- layer-0 epilogue: bias+relu -> swizzled per-wave h0[32][128] bf16 ----
  // byte(r,c) = r*256 + ((c>>3 ^ (r&7))<<4) + (c&7)*2
  char* hbase = (char*)&smH[wv][0];
#pragma unroll
  for (int f = 0; f < 8; ++f) {
    int c = f * 16 + lr;
    float bb = b0[c];
    int chb = (c >> 3) << 4;
    int cwb = (c & 7) << 1;
#pragma unroll
    for (int m = 0; m < 2; ++m)
#pragma unroll
      for (int r = 0; r < 4; ++r) {
        int rr = m * 16 + q * 4 + r;
        *(u16*)(hbase + rr * 256 + (chb ^ ((rr & 7) << 4)) + cwb) =
            f2bf(fmaxf(acc[m][f][r] + bb, 0.f));
      }
  }
  __builtin_amdgcn_wave_barrier();

  // ---- layer 1: [32x128] @ [128x64] ----
  f32x4 acc1[2][4];
#pragma unroll
  for (int m = 0; m < 2; ++m)
#pragma unroll
    for (int f = 0; f < 4; ++f) acc1[m][f] = (f32x4){0.f, 0.f, 0.f, 0.f};
  const u16* bp1 = w1p + lr * 32 + q * 8;
#pragma unroll
  for (int ks = 0; ks < KS1; ++ks) {
    short8 a0 = *(const short8*)(hbase + lr * 256 + (((ks * 4 + q) ^ (lr & 7)) << 4));
    short8 a1 = *(const short8*)(hbase + (16 + lr) * 256 + (((ks * 4 + q) ^ (lr & 7)) << 4));
    short8 b[4];
#pragma unroll
    for (int f = 0; f < 4; ++f)
      b[f] = *(const short8*)(bp1 + ks * 2048 + f * 512);
#pragma unroll
    for (int f = 0; f < 4; ++f) {
      acc1[0][f] = __builtin_amdgcn_mfma_f32_16x16x32_bf16(a0, b[f], acc1[0][f], 0, 0, 0);
      acc1[1][f] = __builtin_amdgcn_mfma_f32_16x16x32_bf16(a1, b[f], acc1[1][f], 0, 0, 0);
    }
  }
  // layer-1 epilogue -> swizzled h1[32][64] (4 KB, overlays dead h0)
  // byte(r,c) = r*128 + ((c>>3 ^ (r&7))<<4) + (c&7)*2
#pragma unroll
  for (int f = 0; f < 4; ++f) {
    int c = f * 16 + lr;
    float bb = b1[c];
    int chb = (c >> 3) << 4;
    int cwb = (c & 7) << 1;
#pragma unroll
    for (int m = 0; m < 2; ++m)
#pragma unroll
      for (int r = 0; r < 4; ++r) {
        int rr = m * 16 + q * 4 + r;
        *(u16*)(hbase + rr * 128 + (chb ^ ((rr & 7) << 4)) + cwb) =
            f2bf(fmaxf(acc1[m][f][r] + bb, 0.f));
      }
  }
  __builtin_amdgcn_wave_barrier();

  // ---- layer 2: [32x64] @ [64x16(10 valid)] ----
  f32x4 acc2[2];
  acc2[0] = (f32x4){0.f, 0.f, 0.f, 0.f};
  acc2[1] = (f32x4){0.f, 0.f, 0.f, 0.f};
  const u16* bp2 = w2p + lr * 32 + q * 8;
#pragma unroll
  for (int ks = 0; ks < KS2; ++ks) {
    short8 a0 = *(const short8*)(hbase + lr * 128 + (((ks * 4 + q) ^ (lr & 7)) << 4));
    short8 a1 = *(const short8*)(hbase + (16 + lr) * 128 + (((ks * 4 + q) ^ (lr & 7)) << 4));
    short8 b = *(const short8*)(bp2 + ks * 512);
    acc2[0] = __builtin_amdgcn_mfma_f32_16x16x32_bf16(a0, b, acc2[0], 0, 0, 0);
    acc2[1] = __builtin_amdgcn_mfma_f32_16x16x32_bf16(a1, b, acc2[1], 0, 0, 0);
  }
  if (lr < D3) {
    float bb = b2[lr];
#pragma unroll
    for (int m = 0; m < 2; ++m)
#pragma unroll
      for (int r = 0; r < 4; ++r) {
        int rowg = rowbase + m * 16 + q * 4 + r;
        out[rowg * D3 + lr] = acc2[m][r] + bb;
      }
  }
}

extern "C" void kernel_launch(void* const* d_in, const int* in_sizes, int n_in,
                              void* d_out, int out_size, void* d_ws, size_t ws_size,
                              hipStream_t stream) {
  const float* X  = (const float*)d_in[0];
  const float* W0 = (const float*)d_in[1];
  const float* W1 = (const float*)d_in[2];
  const float* W2 = (const float*)d_in[3];
  float* out = (float*)d_out;
  char* ws = (char*)d_ws;
  u16* w0p = (u16*)(ws + WS_W0P);
  u16* w1p = (u16*)(ws + WS_W1P);
  u16* w2p = (u16*)(ws + WS_W2P);
  float* b0 = (float*)(ws + WS_B0);
  float* b1 = (float*)(ws + WS_B1);
  float* b2 = (float*)(ws + WS_B2);

  prep_kernel<<<437, 256, 0, stream>>>(W0, W1, W2, w0p, w1p, w2p, b0, b1, b2);
  mlp_fused<<<65536 / 128, 256, 0, stream>>>(X, w0p, w1p, w2p, b0, b1, b2, out);
}